// Round 3
// baseline (9087.716 us; speedup 1.0000x reference)
//
#include <hip/hip_runtime.h>
#include <hip/hip_fp16.h>

typedef _Float16 half8 __attribute__((ext_vector_type(8)));
typedef float f32x4 __attribute__((ext_vector_type(4)));

#define B_ 256
#define SEQ_ 512
#define D_ 256
#define H_ 1024
#define C_ 10
#define S_ 511
#define KB_ 40      // K=1280 / 32
#define NPK_ 2048   // packed output cols per direction (g|i interleaved per 64)
#define NTF_ 128    // NPK/16 fine n-tiles
#define LP_ 84      // LDS row stride (floats): 86,016B total -> forces 1 block/CU (capacity barrier safety)

// ---- workspace byte offsets ----
#define WPK_HALVES (2*KB_*NTF_*512)                    // 5,242,880 halves
#define EMBH_OFF   (WPK_HALVES*2)                      // 10,485,760
#define EMBH_HALVES (SEQ_*D_)                          // 131,072
#define HPK_OFF    (EMBH_OFF + EMBH_HALVES*2)          // 10,747,904
#define HPK_PER_PAR (2*32*16*64*8)                     // 524,288 halves per parity (both dirs)
#define HFIN_OFF   (HPK_OFF + 2*HPK_PER_PAR*2)         // 12,845,056
#define HFIN_FLOATS (2*B_*H_)
#define BIAS_OFF   (HFIN_OFF + HFIN_FLOATS*4)
#define BAR_OFF    (BIAS_OFF + 2*NPK_*4)               // barrier state: 2*128 arrive flags (x16 pad) + 2 rel (x16 pad)
#define BAR_WORDS  (2*128*16 + 2*16)

// Pack fp32 weights -> fp16 in MFMA B-fragment-direct layout, emb -> fp16, biases packed,
// and ZERO the grid-barrier state (ws is re-poisoned before every call).
__global__ void convert_kernel(
    const float* __restrict__ emb,
    const float* __restrict__ Wgx_f, const float* __restrict__ Wgh_f, const float* __restrict__ bg_f,
    const float* __restrict__ Wix_f, const float* __restrict__ Wih_f, const float* __restrict__ bi_f,
    const float* __restrict__ Wgx_b, const float* __restrict__ Wgh_b, const float* __restrict__ bg_b,
    const float* __restrict__ Wix_b, const float* __restrict__ Wih_b, const float* __restrict__ bi_b,
    _Float16* __restrict__ Wpk, _Float16* __restrict__ embh, float* __restrict__ biaspk,
    unsigned* __restrict__ bar)
{
    int idx = blockIdx.x * 256 + threadIdx.x;
    if (idx < WPK_HALVES) {
        int j = idx & 7;
        int L = (idx >> 3) & 63;
        int rest = idx >> 9;
        int ntf = rest & (NTF_ - 1);
        int rest2 = rest >> 7;
        int kb = rest2 % KB_;
        int d  = rest2 / KB_;
        int k = kb*32 + ((L >> 4) << 3) + j;
        int p = (ntf << 4) + (L & 15);
        int gate = (p >> 5) & 1;
        int u = ((p >> 6) << 5) + (p & 31);
        float v;
        if (k < D_) {
            const float* W = d ? (gate ? Wix_b : Wgx_b) : (gate ? Wix_f : Wgx_f);
            v = W[k*H_ + u];
        } else {
            const float* W = d ? (gate ? Wih_b : Wgh_b) : (gate ? Wih_f : Wgh_f);
            v = W[(k - D_)*H_ + u];
        }
        Wpk[idx] = (_Float16)v;
    } else if (idx < WPK_HALVES + EMBH_HALVES) {
        int i2 = idx - WPK_HALVES;
        embh[i2] = (_Float16)emb[i2];
    } else if (idx < WPK_HALVES + EMBH_HALVES + 2*NPK_) {
        int i3 = idx - (WPK_HALVES + EMBH_HALVES);
        int d = i3 >> 11;
        int p = i3 & (NPK_ - 1);
        int gate = (p >> 5) & 1;
        int u = ((p >> 6) << 5) + (p & 31);
        const float* bsrc = d ? (gate ? bi_b : bg_b) : (gate ? bi_f : bg_f);
        biaspk[i3] = bsrc[u];
    } else if (idx < WPK_HALVES + EMBH_HALVES + 2*NPK_ + BAR_WORDS) {
        bar[idx - (WPK_HALVES + EMBH_HALVES + 2*NPK_)] = 0u;
    }
}

// Persistent kernel (plain launch): all 511 timesteps, both directions.
// 256 blocks (forced 1/CU by LDS size) x 256 threads. W fragments + c-state in
// registers; h ping-pongs through global parity buffers; hand-rolled
// per-direction grid barrier (128 blocks each) once per step.
__global__ __launch_bounds__(256, 1) void persistent_kernel(
    const int* __restrict__ x, const _Float16* __restrict__ embh,
    const _Float16* __restrict__ Wpk, const float* __restrict__ biaspk,
    _Float16* __restrict__ hpk, float* __restrict__ hfinal,
    unsigned* __restrict__ bar)
{
    __shared__ float lds[4][64][LP_];

    int dir   = blockIdx.x >> 7;
    int bid   = blockIdx.x & 127;
    int mtblk = bid >> 5;
    int ntb   = bid & 31;
    int w    = threadIdx.x >> 6;
    int lane = threadIdx.x & 63;
    int q    = lane >> 4;
    int c16  = lane & 15;
    int kb0  = w * 10;

    unsigned* arr = bar + dir*(128*16);
    unsigned* rel = bar + 2*128*16 + dir*16;

    const _Float16* Wd = Wpk + (size_t)dir * (KB_*NTF_*512);

    // ---- preload W fragments into registers (160 VGPRs/lane) ----
    half8 wfr[10][4];
    #pragma unroll
    for (int kk = 0; kk < 10; ++kk) {
        #pragma unroll
        for (int nt = 0; nt < 4; ++nt)
            wfr[kk][nt] = *(const half8*)(Wd + (((size_t)(kb0 + kk)*NTF_ + (ntb*4 + nt))*64 + lane)*8);
    }

    // ---- preload epilogue biases ----
    float bzg[2], bzi[2];
    #pragma unroll
    for (int nt = 0; nt < 2; ++nt) {
        bzg[nt] = biaspk[dir*NPK_ + ntb*64 + nt*16 + c16];
        bzi[nt] = biaspk[dir*NPK_ + ntb*64 + (nt + 2)*16 + c16];
    }

    // ---- c-state in registers (fixed ownership across steps) ----
    float creg[2][4];
    #pragma unroll
    for (int nt = 0; nt < 2; ++nt)
        #pragma unroll
        for (int r = 0; r < 4; ++r) creg[nt][r] = 0.f;

    #pragma unroll 1
    for (int t = 0; t < S_; ++t) {
        const _Float16* hrd = hpk + (size_t)(t & 1) * HPK_PER_PAR + dir*(32*16*64*8);
        _Float16*       hwr = hpk + (size_t)((t & 1) ^ 1) * HPK_PER_PAR + dir*(32*16*64*8);
        int t_eff = dir ? (S_ - 1 - t) : t;

        int xr[4] = {0, 0, 0, 0};
        if (w == 0) {                         // only wave 0 handles the x-part kbs
            #pragma unroll
            for (int mt = 0; mt < 4; ++mt)
                xr[mt] = x[(mtblk*64 + mt*16 + c16)*SEQ_ + t_eff];
        }

        f32x4 acc[4][4];
        #pragma unroll
        for (int a = 0; a < 4; ++a)
            #pragma unroll
            for (int b = 0; b < 4; ++b) {
                acc[a][b][0] = 0.f; acc[a][b][1] = 0.f; acc[a][b][2] = 0.f; acc[a][b][3] = 0.f;
            }

        #pragma unroll
        for (int kk = 0; kk < 10; ++kk) {
            int kb = kb0 + kk;
            half8 a[4];
            if (kb < 8) {                     // x part: gather from fp16 emb rows
                #pragma unroll
                for (int mt = 0; mt < 4; ++mt)
                    a[mt] = *(const half8*)(embh + xr[mt]*D_ + kb*32 + q*8);
            } else if (t == 0) {              // h0 = 0
                #pragma unroll
                for (int mt = 0; mt < 4; ++mt) {
                    #pragma unroll
                    for (int e = 0; e < 8; ++e) a[mt][e] = (_Float16)0.f;
                }
            } else {                          // h part: A-fragment-direct layout
                int kb2 = kb - 8;
                #pragma unroll
                for (int mt = 0; mt < 4; ++mt)
                    a[mt] = *(const half8*)(hrd + ((kb2*16 + (mtblk*4 + mt))*64 + lane)*8);
            }
            #pragma unroll
            for (int mt = 0; mt < 4; ++mt) {
                #pragma unroll
                for (int nt = 0; nt < 4; ++nt)
                    acc[mt][nt] = __builtin_amdgcn_mfma_f32_16x16x32_f16(a[mt], wfr[kk][nt], acc[mt][nt], 0, 0, 0);
            }
        }

        // K-split partials -> LDS
        #pragma unroll
        for (int mt = 0; mt < 4; ++mt) {
            #pragma unroll
            for (int nt = 0; nt < 4; ++nt) {
                #pragma unroll
                for (int r = 0; r < 4; ++r)
                    lds[w][mt*16 + q*4 + r][nt*16 + c16] = acc[mt][nt][r];
            }
        }
        __syncthreads();

        // Epilogue: wave w owns rows [16w,16w+16). nt in {0,1}=g cols, +2 = i cols.
        #pragma unroll
        for (int nt = 0; nt < 2; ++nt) {
            #pragma unroll
            for (int r = 0; r < 4; ++r) {
                int ml = 16*w + q*4 + r;
                int cg = nt*16 + c16;
                int ci = (nt + 2)*16 + c16;
                float zg = lds[0][ml][cg] + lds[1][ml][cg] + lds[2][ml][cg] + lds[3][ml][cg];
                float zi = lds[0][ml][ci] + lds[1][ml][ci] + lds[2][ml][ci] + lds[3][ml][ci];
                zg += bzg[nt];
                zi += bzi[nt];
                int u = ntb*32 + nt*16 + c16;
                int m = mtblk*64 + ml;
                float g  = tanhf(zg);
                float ii = 1.f / (1.f + expf(-zi));
                float cn = ii * (g + creg[nt][r]);
                creg[nt][r] = cn;
                float h = tanhf(cn) * ii;
                int kb2 = u >> 5, k5 = u & 31, qd = k5 >> 3, jj = k5 & 7;
                int mt2 = m >> 4, ln2 = (m & 15) + (qd << 4);
                hwr[((kb2*16 + mt2)*64 + ln2)*8 + jj] = (_Float16)h;
                if (t == S_ - 1) hfinal[dir*(B_*H_) + m*H_ + u] = h;
            }
        }

        // ---- per-direction grid barrier (128 blocks) ----
        if (t != S_ - 1) {
            unsigned gen = (unsigned)(t + 1);
            __syncthreads();                  // drains all 4 waves' vmcnt: h-writes are in this XCD's L2
            if (threadIdx.x == 0) {
                __builtin_amdgcn_fence(__ATOMIC_RELEASE, "agent");   // wbl2: publish h-writes
                __hip_atomic_store(&arr[bid*16], gen, __ATOMIC_RELAXED, __HIP_MEMORY_SCOPE_AGENT);
            }
            if (bid == 0) {                   // master: 128 threads poll 128 arrive flags in parallel
                if (threadIdx.x < 128) {
                    while (__hip_atomic_load(&arr[threadIdx.x*16], __ATOMIC_RELAXED, __HIP_MEMORY_SCOPE_AGENT) < gen)
                        __builtin_amdgcn_s_sleep(1);
                }
                __syncthreads();
                if (threadIdx.x == 0)
                    __hip_atomic_store(rel, gen, __ATOMIC_RELEASE, __HIP_MEMORY_SCOPE_AGENT);
            }
            if (threadIdx.x == 0) {
                while (__hip_atomic_load(rel, __ATOMIC_RELAXED, __HIP_MEMORY_SCOPE_AGENT) < gen)
                    __builtin_amdgcn_s_sleep(4);
                __builtin_amdgcn_fence(__ATOMIC_ACQUIRE, "agent");   // inv L1/L2: see remote h-writes
            }
            __syncthreads();
        }
    }
}

// out[b][c] = [hf|hb] @ Wp + bp
__global__ void proj_kernel(const float* __restrict__ hfinal,
                            const float* __restrict__ Wp, const float* __restrict__ bp,
                            float* __restrict__ out)
{
    int b = blockIdx.x;
    int lane = threadIdx.x;
    float s[C_];
    #pragma unroll
    for (int c = 0; c < C_; ++c) s[c] = 0.f;
    for (int j = lane; j < 2*H_; j += 64) {
        float hv = (j < H_) ? hfinal[b*H_ + j] : hfinal[B_*H_ + b*H_ + (j - H_)];
        const float* wr = Wp + j*C_;
        #pragma unroll
        for (int c = 0; c < C_; ++c) s[c] += hv * wr[c];
    }
    #pragma unroll
    for (int off = 32; off > 0; off >>= 1) {
        #pragma unroll
        for (int c = 0; c < C_; ++c) s[c] += __shfl_down(s[c], off);
    }
    if (lane == 0) {
        #pragma unroll
        for (int c = 0; c < C_; ++c) out[b*C_ + c] = s[c] + bp[c];
    }
}

extern "C" void kernel_launch(void* const* d_in, const int* in_sizes, int n_in,
                              void* d_out, int out_size, void* d_ws, size_t ws_size,
                              hipStream_t stream)
{
    const int*   x     = (const int*)d_in[0];
    const float* emb   = (const float*)d_in[1];
    const float* Wgx_f = (const float*)d_in[2];
    const float* Wgh_f = (const float*)d_in[3];
    const float* bg_f  = (const float*)d_in[4];
    const float* Wix_f = (const float*)d_in[5];
    const float* Wih_f = (const float*)d_in[6];
    const float* bi_f  = (const float*)d_in[7];
    const float* Wgx_b = (const float*)d_in[8];
    const float* Wgh_b = (const float*)d_in[9];
    const float* bg_b  = (const float*)d_in[10];
    const float* Wix_b = (const float*)d_in[11];
    const float* Wih_b = (const float*)d_in[12];
    const float* bi_b  = (const float*)d_in[13];
    const float* Wp    = (const float*)d_in[14];
    const float* bp    = (const float*)d_in[15];
    float* out = (float*)d_out;

    char* ws = (char*)d_ws;
    _Float16* Wpk    = (_Float16*)(ws + 0);
    _Float16* embh   = (_Float16*)(ws + EMBH_OFF);
    _Float16* hpk    = (_Float16*)(ws + HPK_OFF);
    float*    hfinal = (float*)(ws + HFIN_OFF);
    float*    biaspk = (float*)(ws + BIAS_OFF);
    unsigned* bar    = (unsigned*)(ws + BAR_OFF);

    int total = WPK_HALVES + EMBH_HALVES + 2*NPK_ + BAR_WORDS;
    convert_kernel<<<(total + 255)/256, 256, 0, stream>>>(
        emb, Wgx_f, Wgh_f, bg_f, Wix_f, Wih_f, bi_f,
        Wgx_b, Wgh_b, bg_b, Wix_b, Wih_b, bi_b, Wpk, embh, biaspk, bar);

    persistent_kernel<<<256, 256, 0, stream>>>(x, embh, Wpk, biaspk, hpk, hfinal, bar);

    proj_kernel<<<B_, 64, 0, stream>>>(hfinal, Wp, bp, out);
}

// Round 4
// 4644.330 us; speedup vs baseline: 1.9567x; 1.9567x over previous
//
#include <hip/hip_runtime.h>
#include <hip/hip_fp16.h>

typedef _Float16 half8 __attribute__((ext_vector_type(8)));
typedef float f32x4 __attribute__((ext_vector_type(4)));
typedef unsigned long long u64;

#define B_ 256
#define SEQ_ 512
#define D_ 256
#define H_ 1024
#define C_ 10
#define S_ 511
#define KB_ 40      // K=1280 / 32
#define NPK_ 2048   // packed output cols per direction (g|i interleaved per 64)
#define NTF_ 128    // NPK/16 fine n-tiles
#define LP_ 84      // LDS row stride (floats): 86,016B total -> forces 1 block/CU (co-residency guarantee)

// ---- workspace byte offsets ----
#define WPK_HALVES (2*KB_*NTF_*512)                    // 5,242,880 halves
#define EMBH_OFF   (WPK_HALVES*2)                      // 10,485,760
#define EMBH_HALVES (SEQ_*D_)                          // 131,072
#define HPK_OFF    (EMBH_OFF + EMBH_HALVES*2)          // 10,747,904
#define HPK_PER_PAR (2*32*16*64*8)                     // 524,288 halves per parity (both dirs)
#define HFIN_OFF   (HPK_OFF + 2*HPK_PER_PAR*2)         // 12,845,056
#define HFIN_FLOATS (2*B_*H_)
#define BIAS_OFF   (HFIN_OFF + HFIN_FLOATS*4)
#define BAR_OFF    (BIAS_OFF + 2*NPK_*4)               // 8 groups x 32 flags x 16-word pad
#define BAR_WORDS  (8*32*16)

__device__ __forceinline__ float fast_sigm(float x) {
    return __builtin_amdgcn_rcpf(1.f + __builtin_amdgcn_exp2f(-1.442695041f * x));
}
__device__ __forceinline__ float fast_tanh(float x) {
    return 1.f - 2.f * __builtin_amdgcn_rcpf(1.f + __builtin_amdgcn_exp2f(2.885390082f * x));
}

// Pack fp32 weights -> fp16 MFMA B-fragment-direct layout, emb -> fp16, biases packed,
// zero barrier flags (ws is re-poisoned before every call).
__global__ void convert_kernel(
    const float* __restrict__ emb,
    const float* __restrict__ Wgx_f, const float* __restrict__ Wgh_f, const float* __restrict__ bg_f,
    const float* __restrict__ Wix_f, const float* __restrict__ Wih_f, const float* __restrict__ bi_f,
    const float* __restrict__ Wgx_b, const float* __restrict__ Wgh_b, const float* __restrict__ bg_b,
    const float* __restrict__ Wix_b, const float* __restrict__ Wih_b, const float* __restrict__ bi_b,
    _Float16* __restrict__ Wpk, _Float16* __restrict__ embh, float* __restrict__ biaspk,
    unsigned* __restrict__ bar)
{
    int idx = blockIdx.x * 256 + threadIdx.x;
    if (idx < WPK_HALVES) {
        int j = idx & 7;
        int L = (idx >> 3) & 63;
        int rest = idx >> 9;
        int ntf = rest & (NTF_ - 1);
        int rest2 = rest >> 7;
        int kb = rest2 % KB_;
        int d  = rest2 / KB_;
        int k = kb*32 + ((L >> 4) << 3) + j;
        int p = (ntf << 4) + (L & 15);
        int gate = (p >> 5) & 1;
        int u = ((p >> 6) << 5) + (p & 31);
        float v;
        if (k < D_) {
            const float* W = d ? (gate ? Wix_b : Wgx_b) : (gate ? Wix_f : Wgx_f);
            v = W[k*H_ + u];
        } else {
            const float* W = d ? (gate ? Wih_b : Wgh_b) : (gate ? Wih_f : Wgh_f);
            v = W[(k - D_)*H_ + u];
        }
        Wpk[idx] = (_Float16)v;
    } else if (idx < WPK_HALVES + EMBH_HALVES) {
        int i2 = idx - WPK_HALVES;
        embh[i2] = (_Float16)emb[i2];
    } else if (idx < WPK_HALVES + EMBH_HALVES + 2*NPK_) {
        int i3 = idx - (WPK_HALVES + EMBH_HALVES);
        int d = i3 >> 11;
        int p = i3 & (NPK_ - 1);
        int gate = (p >> 5) & 1;
        int u = ((p >> 6) << 5) + (p & 31);
        const float* bsrc = d ? (gate ? bi_b : bg_b) : (gate ? bi_f : bg_f);
        biaspk[i3] = bsrc[u];
    } else if (idx < WPK_HALVES + EMBH_HALVES + 2*NPK_ + BAR_WORDS) {
        bar[idx - (WPK_HALVES + EMBH_HALVES + 2*NPK_)] = 0u;
    }
}

// Persistent kernel: all 511 timesteps, both directions.
// blockIdx = ntb*8 + group, group = dir*4 + mtblk (so each 32-block barrier group
// maps to one XCD under round-robin placement). 1 block/CU forced by LDS size.
// W fragments + c-state in registers; h published via write-through system-scope
// stores; per-group all-to-all flag barrier; readers use cached loads after a
// cheap invalidate-only acquire fence.
__global__ __launch_bounds__(256, 1) void persistent_kernel(
    const int* __restrict__ x, const _Float16* __restrict__ embh,
    const _Float16* __restrict__ Wpk, const float* __restrict__ biaspk,
    _Float16* __restrict__ hpk, float* __restrict__ hfinal,
    unsigned* __restrict__ bar)
{
    __shared__ float lds[4][64][LP_];

    int group = blockIdx.x & 7;
    int dir   = group >> 2;
    int mtblk = group & 3;
    int ntb   = blockIdx.x >> 3;
    int w    = threadIdx.x >> 6;
    int lane = threadIdx.x & 63;
    int q    = lane >> 4;
    int c16  = lane & 15;
    int kb0  = w * 10;
    int u0   = q * 8;               // epilogue: 8 consecutive units per thread

    unsigned* gflags = bar + group * (32*16);

    const _Float16* Wd = Wpk + (size_t)dir * (KB_*NTF_*512);

    // ---- preload W fragments into registers (160 VGPRs/lane) ----
    half8 wfr[10][4];
    #pragma unroll
    for (int kk = 0; kk < 10; ++kk) {
        #pragma unroll
        for (int nt = 0; nt < 4; ++nt)
            wfr[kk][nt] = *(const half8*)(Wd + (((size_t)(kb0 + kk)*NTF_ + (ntb*4 + nt))*64 + lane)*8);
    }

    // ---- preload epilogue biases (per new chunk ownership) ----
    float bgr[8], bir[8];
    #pragma unroll
    for (int j = 0; j < 8; ++j) {
        bgr[j] = biaspk[dir*NPK_ + ntb*64 + u0 + j];
        bir[j] = biaspk[dir*NPK_ + ntb*64 + 32 + u0 + j];
    }

    // ---- c-state in registers: thread owns (m = mtblk*64+w*16+c16, u = ntb*32+u0+j) ----
    float creg[8];
    #pragma unroll
    for (int j = 0; j < 8; ++j) creg[j] = 0.f;

    #pragma unroll 1
    for (int t = 0; t < S_; ++t) {
        const _Float16* hrd = hpk + (size_t)(t & 1) * HPK_PER_PAR + dir*(32*16*64*8);
        _Float16*       hwr = hpk + (size_t)((t & 1) ^ 1) * HPK_PER_PAR + dir*(32*16*64*8);
        int t_eff = dir ? (S_ - 1 - t) : t;

        int xr[4] = {0, 0, 0, 0};
        if (w == 0) {                         // only wave 0 handles the x-part kbs
            #pragma unroll
            for (int mt = 0; mt < 4; ++mt)
                xr[mt] = x[(mtblk*64 + mt*16 + c16)*SEQ_ + t_eff];
        }

        f32x4 acc[4][4];
        #pragma unroll
        for (int a = 0; a < 4; ++a)
            #pragma unroll
            for (int b = 0; b < 4; ++b) {
                acc[a][b][0] = 0.f; acc[a][b][1] = 0.f; acc[a][b][2] = 0.f; acc[a][b][3] = 0.f;
            }

        #pragma unroll
        for (int kk = 0; kk < 10; ++kk) {
            int kb = kb0 + kk;
            half8 a[4];
            if (kb < 8) {                     // x part: gather from fp16 emb rows
                #pragma unroll
                for (int mt = 0; mt < 4; ++mt)
                    a[mt] = *(const half8*)(embh + xr[mt]*D_ + kb*32 + q*8);
            } else if (t == 0) {              // h0 = 0
                #pragma unroll
                for (int mt = 0; mt < 4; ++mt) {
                    #pragma unroll
                    for (int e = 0; e < 8; ++e) a[mt][e] = (_Float16)0.f;
                }
            } else {                          // h part: A-fragment-direct layout (cached loads)
                int kb2 = kb - 8;
                #pragma unroll
                for (int mt = 0; mt < 4; ++mt)
                    a[mt] = *(const half8*)(hrd + ((kb2*16 + (mtblk*4 + mt))*64 + lane)*8);
            }
            #pragma unroll
            for (int mt = 0; mt < 4; ++mt) {
                #pragma unroll
                for (int nt = 0; nt < 4; ++nt)
                    acc[mt][nt] = __builtin_amdgcn_mfma_f32_16x16x32_f16(a[mt], wfr[kk][nt], acc[mt][nt], 0, 0, 0);
            }
        }

        // K-split partials -> LDS
        #pragma unroll
        for (int mt = 0; mt < 4; ++mt) {
            #pragma unroll
            for (int nt = 0; nt < 4; ++nt) {
                #pragma unroll
                for (int r = 0; r < 4; ++r)
                    lds[w][mt*16 + q*4 + r][nt*16 + c16] = acc[mt][nt][r];
            }
        }
        __syncthreads();

        // Epilogue: thread -> (m_loc = w*16 + c16, units u0..u0+7). Cols: g = u_loc, i = 32+u_loc.
        {
            int mloc = w*16 + c16;
            int mg   = mtblk*64 + mloc;
            half8 hv;
            float hf[8];
            #pragma unroll
            for (int j = 0; j < 8; ++j) {
                float zg = lds[0][mloc][u0 + j] + lds[1][mloc][u0 + j]
                         + lds[2][mloc][u0 + j] + lds[3][mloc][u0 + j] + bgr[j];
                float zi = lds[0][mloc][32 + u0 + j] + lds[1][mloc][32 + u0 + j]
                         + lds[2][mloc][32 + u0 + j] + lds[3][mloc][32 + u0 + j] + bir[j];
                float g  = fast_tanh(zg);
                float ii = fast_sigm(zi);
                float cn = ii * (g + creg[j]);
                creg[j] = cn;
                float h = fast_tanh(cn) * ii;
                hv[j] = (_Float16)h;
                hf[j] = h;
            }
            // publish h: write-through (system-scope) stores into A-fragment layout.
            u64 two[2];
            __builtin_memcpy(two, &hv, 16);
            u64* base = (u64*)(hwr + ((size_t)((ntb*16 + mtblk*4 + w)*64 + lane) * 8));
            __hip_atomic_store(base,     two[0], __ATOMIC_RELAXED, __HIP_MEMORY_SCOPE_SYSTEM);
            __hip_atomic_store(base + 1, two[1], __ATOMIC_RELAXED, __HIP_MEMORY_SCOPE_SYSTEM);
            if (t == S_ - 1) {
                #pragma unroll
                for (int j = 0; j < 8; ++j)
                    hfinal[dir*(B_*H_) + mg*H_ + ntb*32 + u0 + j] = hf[j];
            }
        }

        // ---- per-group (32-block) barrier ----
        if (t != S_ - 1) {
            unsigned gen = (unsigned)(t + 1);
            __builtin_amdgcn_s_waitcnt(0x0F70);   // vmcnt(0): this wave's h stores visible at coherence point
            __syncthreads();                      // all 4 waves drained (pre-barrier waitcnt)
            if (w == 0) {
                if (threadIdx.x == 0)
                    __hip_atomic_store(&gflags[ntb*16], gen, __ATOMIC_RELAXED, __HIP_MEMORY_SCOPE_SYSTEM);
                unsigned v = gen;
                for (;;) {
                    if (lane < 32)
                        v = __hip_atomic_load(&gflags[lane*16], __ATOMIC_RELAXED, __HIP_MEMORY_SCOPE_SYSTEM);
                    if (__all(v >= gen)) break;
                    __builtin_amdgcn_s_sleep(1);
                }
                __builtin_amdgcn_fence(__ATOMIC_ACQUIRE, "agent");  // invalidate-only (nothing dirty): L1/L2 inv
            }
            __syncthreads();
        }
    }
}

// out[b][c] = [hf|hb] @ Wp + bp
__global__ void proj_kernel(const float* __restrict__ hfinal,
                            const float* __restrict__ Wp, const float* __restrict__ bp,
                            float* __restrict__ out)
{
    int b = blockIdx.x;
    int lane = threadIdx.x;
    float s[C_];
    #pragma unroll
    for (int c = 0; c < C_; ++c) s[c] = 0.f;
    for (int j = lane; j < 2*H_; j += 64) {
        float hv = (j < H_) ? hfinal[b*H_ + j] : hfinal[B_*H_ + b*H_ + (j - H_)];
        const float* wr = Wp + j*C_;
        #pragma unroll
        for (int c = 0; c < C_; ++c) s[c] += hv * wr[c];
    }
    #pragma unroll
    for (int off = 32; off > 0; off >>= 1) {
        #pragma unroll
        for (int c = 0; c < C_; ++c) s[c] += __shfl_down(s[c], off);
    }
    if (lane == 0) {
        #pragma unroll
        for (int c = 0; c < C_; ++c) out[b*C_ + c] = s[c] + bp[c];
    }
}

extern "C" void kernel_launch(void* const* d_in, const int* in_sizes, int n_in,
                              void* d_out, int out_size, void* d_ws, size_t ws_size,
                              hipStream_t stream)
{
    const int*   x     = (const int*)d_in[0];
    const float* emb   = (const float*)d_in[1];
    const float* Wgx_f = (const float*)d_in[2];
    const float* Wgh_f = (const float*)d_in[3];
    const float* bg_f  = (const float*)d_in[4];
    const float* Wix_f = (const float*)d_in[5];
    const float* Wih_f = (const float*)d_in[6];
    const float* bi_f  = (const float*)d_in[7];
    const float* Wgx_b = (const float*)d_in[8];
    const float* Wgh_b = (const float*)d_in[9];
    const float* bg_b  = (const float*)d_in[10];
    const float* Wix_b = (const float*)d_in[11];
    const float* Wih_b = (const float*)d_in[12];
    const float* bi_b  = (const float*)d_in[13];
    const float* Wp    = (const float*)d_in[14];
    const float* bp    = (const float*)d_in[15];
    float* out = (float*)d_out;

    char* ws = (char*)d_ws;
    _Float16* Wpk    = (_Float16*)(ws + 0);
    _Float16* embh   = (_Float16*)(ws + EMBH_OFF);
    _Float16* hpk    = (_Float16*)(ws + HPK_OFF);
    float*    hfinal = (float*)(ws + HFIN_OFF);
    float*    biaspk = (float*)(ws + BIAS_OFF);
    unsigned* bar    = (unsigned*)(ws + BAR_OFF);

    int total = WPK_HALVES + EMBH_HALVES + 2*NPK_ + BAR_WORDS;
    convert_kernel<<<(total + 255)/256, 256, 0, stream>>>(
        emb, Wgx_f, Wgh_f, bg_f, Wix_f, Wih_f, bi_f,
        Wgx_b, Wgh_b, bg_b, Wix_b, Wih_b, bi_b, Wpk, embh, biaspk, bar);

    persistent_kernel<<<256, 256, 0, stream>>>(x, embh, Wpk, biaspk, hpk, hfinal, bar);

    proj_kernel<<<B_, 64, 0, stream>>>(hfinal, Wp, bp, out);
}

// Round 5
// 4486.254 us; speedup vs baseline: 2.0257x; 1.0352x over previous
//
#include <hip/hip_runtime.h>
#include <hip/hip_fp16.h>

typedef _Float16 half8 __attribute__((ext_vector_type(8)));
typedef float f32x4 __attribute__((ext_vector_type(4)));
typedef unsigned long long u64;

#define B_ 256
#define SEQ_ 512
#define D_ 256
#define H_ 1024
#define C_ 10
#define S_ 511
#define KB_ 40      // K=1280 / 32
#define NPK_ 2048   // packed output cols per direction (g|i interleaved per 64)
#define NTF_ 128    // NPK/16 fine n-tiles
#define LP_ 84      // LDS row stride (floats): 86,016B total -> forces 1 block/CU (co-residency guarantee)

// ---- workspace byte offsets ----
#define WPK_HALVES (2*KB_*NTF_*512)                    // 5,242,880 halves
#define EMBH_OFF   (WPK_HALVES*2)                      // 10,485,760
#define EMBH_HALVES (SEQ_*D_)                          // 131,072
#define HPK_OFF    (EMBH_OFF + EMBH_HALVES*2)          // 10,747,904
#define HPK_PER_PAR (2*32*16*64*8)                     // 524,288 halves per parity (both dirs)
#define HFIN_OFF   (HPK_OFF + 2*HPK_PER_PAR*2)         // 12,845,056
#define HFIN_FLOATS (2*B_*H_)
#define BIAS_OFF   (HFIN_OFF + HFIN_FLOATS*4)
#define BAR_OFF    (BIAS_OFF + 2*NPK_*4)               // 8 groups x 32 flags x 16-word pad
#define BAR_WORDS  (8*32*16)
#define XT_OFF     (BAR_OFF + BAR_WORDS*4)             // transposed x: [SEQ][B] ints
#define XT_INTS    (SEQ_*B_)

__device__ __forceinline__ float fast_sigm(float x) {
    return __builtin_amdgcn_rcpf(1.f + __builtin_amdgcn_exp2f(-1.442695041f * x));
}
__device__ __forceinline__ float fast_tanh(float x) {
    return 1.f - 2.f * __builtin_amdgcn_rcpf(1.f + __builtin_amdgcn_exp2f(2.885390082f * x));
}
__device__ __forceinline__ half8 load_h_uc(const _Float16* p) {
    u64 two[2];
    two[0] = __hip_atomic_load((const u64*)p,     __ATOMIC_RELAXED, __HIP_MEMORY_SCOPE_SYSTEM);
    two[1] = __hip_atomic_load((const u64*)p + 1, __ATOMIC_RELAXED, __HIP_MEMORY_SCOPE_SYSTEM);
    half8 r; __builtin_memcpy(&r, two, 16); return r;
}

// Pack fp32 weights -> fp16 MFMA B-fragment-direct layout, emb -> fp16, biases packed,
// x -> transposed xT[t][m], zero barrier flags (ws is re-poisoned before every call).
__global__ void convert_kernel(
    const int* __restrict__ x, const float* __restrict__ emb,
    const float* __restrict__ Wgx_f, const float* __restrict__ Wgh_f, const float* __restrict__ bg_f,
    const float* __restrict__ Wix_f, const float* __restrict__ Wih_f, const float* __restrict__ bi_f,
    const float* __restrict__ Wgx_b, const float* __restrict__ Wgh_b, const float* __restrict__ bg_b,
    const float* __restrict__ Wix_b, const float* __restrict__ Wih_b, const float* __restrict__ bi_b,
    _Float16* __restrict__ Wpk, _Float16* __restrict__ embh, float* __restrict__ biaspk,
    unsigned* __restrict__ bar, int* __restrict__ xT)
{
    int idx = blockIdx.x * 256 + threadIdx.x;
    if (idx < WPK_HALVES) {
        int j = idx & 7;
        int L = (idx >> 3) & 63;
        int rest = idx >> 9;
        int ntf = rest & (NTF_ - 1);
        int rest2 = rest >> 7;
        int kb = rest2 % KB_;
        int d  = rest2 / KB_;
        int k = kb*32 + ((L >> 4) << 3) + j;
        int p = (ntf << 4) + (L & 15);
        int gate = (p >> 5) & 1;
        int u = ((p >> 6) << 5) + (p & 31);
        float v;
        if (k < D_) {
            const float* W = d ? (gate ? Wix_b : Wgx_b) : (gate ? Wix_f : Wgx_f);
            v = W[k*H_ + u];
        } else {
            const float* W = d ? (gate ? Wih_b : Wgh_b) : (gate ? Wih_f : Wgh_f);
            v = W[(k - D_)*H_ + u];
        }
        Wpk[idx] = (_Float16)v;
    } else if (idx < WPK_HALVES + EMBH_HALVES) {
        int i2 = idx - WPK_HALVES;
        embh[i2] = (_Float16)emb[i2];
    } else if (idx < WPK_HALVES + EMBH_HALVES + 2*NPK_) {
        int i3 = idx - (WPK_HALVES + EMBH_HALVES);
        int d = i3 >> 11;
        int p = i3 & (NPK_ - 1);
        int gate = (p >> 5) & 1;
        int u = ((p >> 6) << 5) + (p & 31);
        const float* bsrc = d ? (gate ? bi_b : bg_b) : (gate ? bi_f : bg_f);
        biaspk[i3] = bsrc[u];
    } else if (idx < WPK_HALVES + EMBH_HALVES + 2*NPK_ + BAR_WORDS) {
        bar[idx - (WPK_HALVES + EMBH_HALVES + 2*NPK_)] = 0u;
    } else if (idx < WPK_HALVES + EMBH_HALVES + 2*NPK_ + BAR_WORDS + XT_INTS) {
        int i5 = idx - (WPK_HALVES + EMBH_HALVES + 2*NPK_ + BAR_WORDS);
        int t = i5 >> 8;
        int m = i5 & (B_ - 1);
        xT[i5] = x[m*SEQ_ + t];
    }
}

// Persistent kernel: all 511 timesteps, both directions.
// blockIdx = ntb*8 + group, group = dir*4 + mtblk. 1 block/CU forced by LDS size.
// W + c-state in registers. Each wave owns 2 x-kbs + 8 h-kbs: x-part MFMAs
// overlap the producer wait. h exchanged via UC (system-scope) stores+loads:
// NO cache-maintenance fences anywhere in the loop.
__global__ __launch_bounds__(256, 1) void persistent_kernel(
    const int* __restrict__ xT, const _Float16* __restrict__ embh,
    const _Float16* __restrict__ Wpk, const float* __restrict__ biaspk,
    _Float16* __restrict__ hpk, float* __restrict__ hfinal,
    unsigned* __restrict__ bar)
{
    __shared__ float lds[4][64][LP_];

    int group = blockIdx.x & 7;
    int dir   = group >> 2;
    int mtblk = group & 3;
    int ntb   = blockIdx.x >> 3;
    int w    = threadIdx.x >> 6;
    int lane = threadIdx.x & 63;
    int q    = lane >> 4;
    int c16  = lane & 15;
    int u0   = q * 8;               // epilogue: 8 consecutive units per thread

    unsigned* gflags = bar + group * (32*16);

    const _Float16* Wd = Wpk + (size_t)dir * (KB_*NTF_*512);

    // ---- preload W fragments into registers (160 VGPRs/lane) ----
    // wave w: x-kbs {2w, 2w+1}, h-kbs {8+8w .. 15+8w}
    half8 wfx[2][4], wfh[8][4];
    #pragma unroll
    for (int kx = 0; kx < 2; ++kx) {
        #pragma unroll
        for (int nt = 0; nt < 4; ++nt)
            wfx[kx][nt] = *(const half8*)(Wd + (((size_t)(2*w + kx)*NTF_ + (ntb*4 + nt))*64 + lane)*8);
    }
    #pragma unroll
    for (int i = 0; i < 8; ++i) {
        #pragma unroll
        for (int nt = 0; nt < 4; ++nt)
            wfh[i][nt] = *(const half8*)(Wd + (((size_t)(8 + 8*w + i)*NTF_ + (ntb*4 + nt))*64 + lane)*8);
    }

    // ---- preload epilogue biases ----
    float bgr[8], bir[8];
    #pragma unroll
    for (int j = 0; j < 8; ++j) {
        bgr[j] = biaspk[dir*NPK_ + ntb*64 + u0 + j];
        bir[j] = biaspk[dir*NPK_ + ntb*64 + 32 + u0 + j];
    }

    // ---- c-state in registers: thread owns (m = mtblk*64+w*16+c16, u = ntb*32+u0+j) ----
    float creg[8];
    #pragma unroll
    for (int j = 0; j < 8; ++j) creg[j] = 0.f;

    #pragma unroll 1
    for (int t = 0; t < S_; ++t) {
        const _Float16* hrd = hpk + (size_t)(t & 1) * HPK_PER_PAR + dir*(32*16*64*8);
        _Float16*       hwr = hpk + (size_t)((t & 1) ^ 1) * HPK_PER_PAR + dir*(32*16*64*8);
        int t_eff = dir ? (S_ - 1 - t) : t;

        int xr[4];
        #pragma unroll
        for (int mt = 0; mt < 4; ++mt)
            xr[mt] = xT[t_eff*B_ + mtblk*64 + mt*16 + c16];

        f32x4 acc[4][4];
        #pragma unroll
        for (int a = 0; a < 4; ++a)
            #pragma unroll
            for (int b = 0; b < 4; ++b) {
                acc[a][b][0] = 0.f; acc[a][b][1] = 0.f; acc[a][b][2] = 0.f; acc[a][b][3] = 0.f;
            }

        // ---- x-part (independent of h): overlaps producer wait ----
        #pragma unroll
        for (int kx = 0; kx < 2; ++kx) {
            int kb = 2*w + kx;
            half8 a[4];
            #pragma unroll
            for (int mt = 0; mt < 4; ++mt)
                a[mt] = *(const half8*)(embh + xr[mt]*D_ + kb*32 + q*8);
            #pragma unroll
            for (int mt = 0; mt < 4; ++mt) {
                #pragma unroll
                for (int nt = 0; nt < 4; ++nt)
                    acc[mt][nt] = __builtin_amdgcn_mfma_f32_16x16x32_f16(a[mt], wfx[kx][nt], acc[mt][nt], 0, 0, 0);
            }
        }

        if (t > 0) {
            // ---- wait for all 32 producers of this group to have published step t's h ----
            unsigned gen = (unsigned)t;
            unsigned v = gen;
            for (;;) {
                if (lane < 32)
                    v = __hip_atomic_load(&gflags[lane*16], __ATOMIC_RELAXED, __HIP_MEMORY_SCOPE_SYSTEM);
                if (__all(v >= gen)) break;
                __builtin_amdgcn_s_sleep(1);
            }
            // ---- h-part: UC loads straight from coherence point (no fence needed) ----
            #pragma unroll
            for (int i = 0; i < 8; ++i) {
                int kb2 = 8*w + i;
                half8 a[4];
                #pragma unroll
                for (int mt = 0; mt < 4; ++mt)
                    a[mt] = load_h_uc(hrd + (size_t)((kb2*16 + (mtblk*4 + mt))*64 + lane)*8);
                #pragma unroll
                for (int mt = 0; mt < 4; ++mt) {
                    #pragma unroll
                    for (int nt = 0; nt < 4; ++nt)
                        acc[mt][nt] = __builtin_amdgcn_mfma_f32_16x16x32_f16(a[mt], wfh[i][nt], acc[mt][nt], 0, 0, 0);
                }
            }
        }

        // K-split partials -> LDS
        #pragma unroll
        for (int mt = 0; mt < 4; ++mt) {
            #pragma unroll
            for (int nt = 0; nt < 4; ++nt) {
                #pragma unroll
                for (int r = 0; r < 4; ++r)
                    lds[w][mt*16 + q*4 + r][nt*16 + c16] = acc[mt][nt][r];
            }
        }
        __syncthreads();

        // Epilogue: thread -> (m_loc = w*16 + c16, units u0..u0+7). Cols: g = u_loc, i = 32+u_loc.
        {
            int mloc = w*16 + c16;
            int mg   = mtblk*64 + mloc;
            half8 hv;
            float hf[8];
            #pragma unroll
            for (int j = 0; j < 8; ++j) {
                float zg = lds[0][mloc][u0 + j] + lds[1][mloc][u0 + j]
                         + lds[2][mloc][u0 + j] + lds[3][mloc][u0 + j] + bgr[j];
                float zi = lds[0][mloc][32 + u0 + j] + lds[1][mloc][32 + u0 + j]
                         + lds[2][mloc][32 + u0 + j] + lds[3][mloc][32 + u0 + j] + bir[j];
                float g  = fast_tanh(zg);
                float ii = fast_sigm(zi);
                float cn = ii * (g + creg[j]);
                creg[j] = cn;
                float h = fast_tanh(cn) * ii;
                hv[j] = (_Float16)h;
                hf[j] = h;
            }
            // publish h: write-through (system-scope) stores into A-fragment layout.
            u64 two[2];
            __builtin_memcpy(two, &hv, 16);
            u64* base = (u64*)(hwr + ((size_t)((ntb*16 + mtblk*4 + w)*64 + lane) * 8));
            __hip_atomic_store(base,     two[0], __ATOMIC_RELAXED, __HIP_MEMORY_SCOPE_SYSTEM);
            __hip_atomic_store(base + 1, two[1], __ATOMIC_RELAXED, __HIP_MEMORY_SCOPE_SYSTEM);
            if (t == S_ - 1) {
                #pragma unroll
                for (int j = 0; j < 8; ++j)
                    hfinal[dir*(B_*H_) + mg*H_ + ntb*32 + u0 + j] = hf[j];
            }
        }

        // ---- publish completion flag (no cache maintenance) ----
        if (t != S_ - 1) {
            __builtin_amdgcn_s_waitcnt(0x0F70);   // vmcnt(0): this wave's UC h-stores acked at coherence point
            __syncthreads();                      // all 4 waves drained; also protects LDS reuse
            if (threadIdx.x == 0)
                __hip_atomic_store(&gflags[ntb*16], (unsigned)(t + 1), __ATOMIC_RELAXED, __HIP_MEMORY_SCOPE_SYSTEM);
        }
    }
}

// out[b][c] = [hf|hb] @ Wp + bp
__global__ void proj_kernel(const float* __restrict__ hfinal,
                            const float* __restrict__ Wp, const float* __restrict__ bp,
                            float* __restrict__ out)
{
    int b = blockIdx.x;
    int lane = threadIdx.x;
    float s[C_];
    #pragma unroll
    for (int c = 0; c < C_; ++c) s[c] = 0.f;
    for (int j = lane; j < 2*H_; j += 64) {
        float hv = (j < H_) ? hfinal[b*H_ + j] : hfinal[B_*H_ + b*H_ + (j - H_)];
        const float* wr = Wp + j*C_;
        #pragma unroll
        for (int c = 0; c < C_; ++c) s[c] += hv * wr[c];
    }
    #pragma unroll
    for (int off = 32; off > 0; off >>= 1) {
        #pragma unroll
        for (int c = 0; c < C_; ++c) s[c] += __shfl_down(s[c], off);
    }
    if (lane == 0) {
        #pragma unroll
        for (int c = 0; c < C_; ++c) out[b*C_ + c] = s[c] + bp[c];
    }
}

extern "C" void kernel_launch(void* const* d_in, const int* in_sizes, int n_in,
                              void* d_out, int out_size, void* d_ws, size_t ws_size,
                              hipStream_t stream)
{
    const int*   x     = (const int*)d_in[0];
    const float* emb   = (const float*)d_in[1];
    const float* Wgx_f = (const float*)d_in[2];
    const float* Wgh_f = (const float*)d_in[3];
    const float* bg_f  = (const float*)d_in[4];
    const float* Wix_f = (const float*)d_in[5];
    const float* Wih_f = (const float*)d_in[6];
    const float* bi_f  = (const float*)d_in[7];
    const float* Wgx_b = (const float*)d_in[8];
    const float* Wgh_b = (const float*)d_in[9];
    const float* bg_b  = (const float*)d_in[10];
    const float* Wix_b = (const float*)d_in[11];
    const float* Wih_b = (const float*)d_in[12];
    const float* bi_b  = (const float*)d_in[13];
    const float* Wp    = (const float*)d_in[14];
    const float* bp    = (const float*)d_in[15];
    float* out = (float*)d_out;

    char* ws = (char*)d_ws;
    _Float16* Wpk    = (_Float16*)(ws + 0);
    _Float16* embh   = (_Float16*)(ws + EMBH_OFF);
    _Float16* hpk    = (_Float16*)(ws + HPK_OFF);
    float*    hfinal = (float*)(ws + HFIN_OFF);
    float*    biaspk = (float*)(ws + BIAS_OFF);
    unsigned* bar    = (unsigned*)(ws + BAR_OFF);
    int*      xT     = (int*)(ws + XT_OFF);

    int total = WPK_HALVES + EMBH_HALVES + 2*NPK_ + BAR_WORDS + XT_INTS;
    convert_kernel<<<(total + 255)/256, 256, 0, stream>>>(
        x, emb, Wgx_f, Wgh_f, bg_f, Wix_f, Wih_f, bi_f,
        Wgx_b, Wgh_b, bg_b, Wix_b, Wih_b, bi_b, Wpk, embh, biaspk, bar, xT);

    persistent_kernel<<<256, 256, 0, stream>>>(xT, embh, Wpk, biaspk, hpk, hfinal, bar);

    proj_kernel<<<B_, 64, 0, stream>>>(hfinal, Wp, bp, out);
}